// Round 7
// baseline (957.101 us; speedup 1.0000x reference)
//
#include <hip/hip_runtime.h>
#include <hip/hip_bf16.h>
#include <hip/hip_fp16.h>

// ChebNet: N=100000 nodes, E=3.2M edges, K=4, 128 -> 128(relu) -> 64 -> log_softmax
// Clenshaw form: sum_k T_k(L) x @ W_k == Clenshaw(L, y_k), y_k = x @ W_k.
// R7: k_prop MLP doubled (4-deep gather pipeline; R3->R4 showed rate ~ in-flight
//     requests: 1->2 gathers gave 2.1->3.7 TB/s) + nontemporal hints on streamed
//     operands (ed/A/B/final-out) so L2/L3 keeps the gather working set. dsth
//     stores stay cached (they are the next prop's gather source).

#define NN 100000
#define NE 3200000
#define NB 782          // ceil(NN/128) buckets of 128 rows

using half8 = __attribute__((ext_vector_type(8))) _Float16;
using floatx4 = __attribute__((ext_vector_type(4))) float;

// ---------------------------------------------------------------- pass 1: bucket counts
__global__ __launch_bounds__(256) void k_bcount(const int* __restrict__ erow,
                                                int* __restrict__ bcnt) {
    __shared__ int hist[NB];
    const int t = threadIdx.x;
    const int e0 = blockIdx.x * 8192 + t * 32;
    for (int b = t; b < NB; b += 256) hist[b] = 0;
    __syncthreads();
#pragma unroll
    for (int j = 0; j < 8; ++j) {
        int idx = e0 + j * 4;
        if (idx < NE) {
            int4 r4 = *(const int4*)(erow + idx);
            atomicAdd(&hist[r4.x >> 7], 1);
            atomicAdd(&hist[r4.y >> 7], 1);
            atomicAdd(&hist[r4.z >> 7], 1);
            atomicAdd(&hist[r4.w >> 7], 1);
        }
    }
    __syncthreads();
    for (int b = t; b < NB; b += 256)
        if (hist[b] > 0) atomicAdd(&bcnt[b], hist[b]);
}

// ---------------------------------------------------------------- scan bucket counts -> bbase, bcur
__global__ __launch_bounds__(256) void k_bscan(const int* __restrict__ bcnt,
                                               int* __restrict__ bbase,
                                               int* __restrict__ bcur) {
    __shared__ int sm[256];
    const int t = threadIdx.x;
    int v[4];
    int s = 0;
#pragma unroll
    for (int j = 0; j < 4; ++j) {
        int idx = t * 4 + j;
        v[j] = (idx < NB) ? bcnt[idx] : 0;
        s += v[j];
    }
    sm[t] = s; __syncthreads();
    for (int st = 1; st < 256; st <<= 1) {
        int a = (t >= st) ? sm[t - st] : 0;
        __syncthreads();
        sm[t] += a;
        __syncthreads();
    }
    int ex = (t == 0) ? 0 : sm[t - 1];
#pragma unroll
    for (int j = 0; j < 4; ++j) {
        int idx = t * 4 + j;
        if (idx < NB) { bbase[idx] = ex; bcur[idx] = ex; }
        ex += v[j];
    }
    if (t == 255) bbase[NB] = NE;
}

// ---------------------------------------------------------------- pass 2: bucket edges into staging S
__global__ __launch_bounds__(256) void k_bin(const int* __restrict__ erow,
                                             const int* __restrict__ ecol,
                                             int* __restrict__ bcur,
                                             unsigned int* __restrict__ S) {
    __shared__ int hist[NB];
    __shared__ int base[NB];
    __shared__ int cnt[NB];
    const int t = threadIdx.x;
    const int e0 = blockIdx.x * 8192 + t * 32;

    for (int b = t; b < NB; b += 256) { hist[b] = 0; cnt[b] = 0; }
    __syncthreads();

#pragma unroll
    for (int j = 0; j < 8; ++j) {
        int idx = e0 + j * 4;
        if (idx < NE) {
            int4 r4 = *(const int4*)(erow + idx);
            atomicAdd(&hist[r4.x >> 7], 1);
            atomicAdd(&hist[r4.y >> 7], 1);
            atomicAdd(&hist[r4.z >> 7], 1);
            atomicAdd(&hist[r4.w >> 7], 1);
        }
    }
    __syncthreads();

    for (int b = t; b < NB; b += 256)
        if (hist[b] > 0) base[b] = atomicAdd(&bcur[b], hist[b]);
    __syncthreads();

#pragma unroll
    for (int j = 0; j < 8; ++j) {
        int idx = e0 + j * 4;
        if (idx < NE) {
            int4 r4 = *(const int4*)(erow + idx);
            int4 c4 = *(const int4*)(ecol + idx);
            int rr[4] = {r4.x, r4.y, r4.z, r4.w};
            int cc[4] = {c4.x, c4.y, c4.z, c4.w};
#pragma unroll
            for (int q = 0; q < 4; ++q) {
                int b = rr[q] >> 7;
                int off = atomicAdd(&cnt[b], 1);
                S[base[b] + off] = ((unsigned)(rr[q] & 127) << 17) | (unsigned)cc[q];
            }
        }
    }
}

// ---------------------------------------------------------------- per-bucket row_ptr + dis
__global__ __launch_bounds__(256) void k_rowptr(const int* __restrict__ bbase,
                                                const unsigned int* __restrict__ S,
                                                int* __restrict__ row_ptr,
                                                float* __restrict__ dis) {
    __shared__ int hist[128];
    __shared__ int sc[128];
    const int b = blockIdx.x;
    const int t = threadIdx.x;
    const int r0 = b * 128;
    const int rows = (r0 + 128 <= NN) ? 128 : (NN - r0);
    if (t < 128) hist[t] = 0;
    __syncthreads();
    const int s = bbase[b];
    const int e = bbase[b + 1];
    for (int i = s + t; i < e; i += 256)
        atomicAdd(&hist[S[i] >> 17], 1);
    __syncthreads();
    if (t < 128) sc[t] = hist[t];
    __syncthreads();
    for (int st = 1; st < 128; st <<= 1) {
        int a = (t >= st && t < 128) ? sc[t - st] : 0;
        __syncthreads();
        if (t < 128) sc[t] += a;
        __syncthreads();
    }
    if (t < rows) {
        row_ptr[r0 + t] = s + ((t == 0) ? 0 : sc[t - 1]);
        int d = hist[t];
        dis[r0 + t] = (d > 0) ? rsqrtf((float)d) : 0.0f;
    }
    if (b == 0 && t == 0) row_ptr[NN] = NE;
}

// ---------------------------------------------------------------- pass 3: within-bucket placement
__global__ __launch_bounds__(256) void k_place(const int* __restrict__ row_ptr,
                                               const float* __restrict__ dis,
                                               const unsigned int* __restrict__ S,
                                               int2* __restrict__ ed) {
    __shared__ int cur[128];
    __shared__ float disr[128];
    const int b = blockIdx.x;
    const int t = threadIdx.x;
    const int r0 = b * 128;
    const int rows = (r0 + 128 <= NN) ? 128 : (NN - r0);
    if (t < rows) {
        cur[t] = row_ptr[r0 + t];
        disr[t] = dis[r0 + t];
    }
    __syncthreads();
    const int s = row_ptr[r0];
    const int e = row_ptr[r0 + rows];
    for (int i = s + t; i < e; i += 256) {
        unsigned v = S[i];
        int c = v & 131071;
        int rl = v >> 17;
        float wv = -disr[rl] * dis[c];
        int pos = atomicAdd(&cur[rl], 1);
        ed[pos] = make_int2(c, __float_as_int(wv));
    }
}

// ---------------------------------------------------------------- W transpose -> fp16 [N][K]
__global__ void k_wt(const float* __restrict__ W1, const float* __restrict__ W2,
                     __half* __restrict__ Wt1, __half* __restrict__ Wt2) {
    int tid = blockIdx.x * 256 + threadIdx.x;
    if (tid < 512 * 128) {
        int n = tid >> 7, k = tid & 127;
        Wt1[tid] = __float2half_rn(W1[(((n >> 7) * 128) + k) * 128 + (n & 127)]);
    } else {
        int t2 = tid - 512 * 128;
        if (t2 < 256 * 128) {
            int n = t2 >> 7, k = t2 & 127;
            Wt2[t2] = __float2half_rn(W2[(((n >> 6) * 128) + k) * 64 + (n & 63)]);
        }
    }
}

// ---------------------------------------------------------------- MFMA GEMM  Y = X @ Wt^T
template <int OUTC, typename TX>
__global__ __launch_bounds__(256) void k_mm(const TX* __restrict__ X,
                                            const __half* __restrict__ Wt,
                                            __half* __restrict__ Y) {
    __shared__ __half As[128 * 136];
    const int t = threadIdx.x;
    const int lane = t & 63;
    const int w = t >> 6;
    const int r0 = blockIdx.x * 128;
    const int n0 = blockIdx.y * 128;

    if constexpr (sizeof(TX) == 4) {
#pragma unroll
        for (int i = 0; i < 16; ++i) {
            int v = t + i * 256;
            int row = v >> 5, c4 = v & 31;
            float4 xv = make_float4(0.f, 0.f, 0.f, 0.f);
            if (r0 + row < NN) xv = *(const float4*)((const float*)X + (size_t)(r0 + row) * 128 + c4 * 4);
            __half2* p = (__half2*)(As + row * 136 + c4 * 4);
            p[0] = __float22half2_rn(make_float2(xv.x, xv.y));
            p[1] = __float22half2_rn(make_float2(xv.z, xv.w));
        }
    } else {
#pragma unroll
        for (int i = 0; i < 8; ++i) {
            int v = t + i * 256;
            int row = v >> 4, c8 = v & 15;
            uint4 xv = make_uint4(0, 0, 0, 0);
            if (r0 + row < NN) xv = *(const uint4*)((const __half*)X + (size_t)(r0 + row) * 128 + c8 * 8);
            *(uint4*)(As + row * 136 + c8 * 8) = xv;
        }
    }
    __syncthreads();

    const int m = lane & 15, quad = lane >> 4;
    floatx4 acc[2][8] = {};
    const __half* wb = Wt + (size_t)(n0 + m) * 128 + quad * 8;
    const __half* ab = As + (w * 32 + m) * 136 + quad * 8;

#pragma unroll
    for (int ks = 0; ks < 4; ++ks) {
        half8 a0 = *(const half8*)(ab + ks * 32);
        half8 a1 = *(const half8*)(ab + 16 * 136 + ks * 32);
#pragma unroll
        for (int nt = 0; nt < 8; ++nt) {
            half8 b = *(const half8*)(wb + (size_t)nt * 16 * 128 + ks * 32);
            acc[0][nt] = __builtin_amdgcn_mfma_f32_16x16x32_f16(a0, b, acc[0][nt], 0, 0, 0);
            acc[1][nt] = __builtin_amdgcn_mfma_f32_16x16x32_f16(a1, b, acc[1][nt], 0, 0, 0);
        }
    }

    __syncthreads();
#pragma unroll
    for (int mt = 0; mt < 2; ++mt)
#pragma unroll
        for (int nt = 0; nt < 8; ++nt)
#pragma unroll
            for (int rg = 0; rg < 4; ++rg)
                As[(w * 32 + mt * 16 + quad * 4 + rg) * 136 + nt * 16 + m] =
                    __float2half_rn(acc[mt][nt][rg]);
    __syncthreads();

#pragma unroll
    for (int i = 0; i < 8; ++i) {
        int v = t + i * 256;
        int row = v >> 4, c8 = v & 15;
        int node = r0 + row;
        if (node < NN) {
            uint4 val = *(const uint4*)(As + row * 136 + c8 * 8);
            int ng = n0 + c8 * 8;
            __half* dst;
            if (OUTC == 128) dst = Y + ((size_t)(ng >> 7) * NN + node) * 128 + (ng & 127);
            else             dst = Y + ((size_t)(ng >> 6) * NN + node) * 64 + (ng & 63);
            *(uint4*)dst = val;
        }
    }
}

// ---------------------------------------------------------------- propagation (SpMM, 4-deep pipeline)
// dst[r][:] = scale * sum_e w_e * src[col_e][:] + A[r][:] + betaB*B[r][:] (+bias, relu, lsm)
template <int C>
__global__ __launch_bounds__(256) void k_prop(const int* __restrict__ rp,
                                              const int2* __restrict__ ed,
                                              const __half* __restrict__ src,
                                              const __half* __restrict__ A,
                                              const __half* __restrict__ B,
                                              const float* __restrict__ bias,
                                              float scale, float betaB, int do_relu,
                                              int do_lsm,
                                              __half* __restrict__ dsth,
                                              float* __restrict__ dstf) {
    constexpr int LPE = C / 8;     // lanes per edge (half8 each)
    constexpr int EG = 64 / LPE;   // concurrent edge groups per wave
    constexpr int PD = 4;          // pipeline depth (gathers in flight)
    const int wid = threadIdx.x >> 6;
    const int lane = threadIdx.x & 63;
    const int r = blockIdx.x * 4 + wid;
    if (r >= NN) return;
    const int e0 = rp[r], e1 = rp[r + 1];
    const int eg = lane / LPE, li = lane % LPE;

    auto ldmeta = [&](int idx) -> int2 {
        if (idx < e1) {
            unsigned long long u =
                __builtin_nontemporal_load((const unsigned long long*)(ed + idx));
            return make_int2((int)(unsigned)u, (int)(u >> 32));
        }
        return make_int2(0, 0);
    };

    float acc[8] = {};
    int e = e0 + eg;
    int2 m[PD];
#pragma unroll
    for (int j = 0; j < PD; ++j) m[j] = ldmeta(e + j * EG);

    const int nit = (e1 - e0 + PD * EG - 1) / (PD * EG);   // wave-uniform
    for (int it = 0; it < nit; ++it) {
        half8 v[PD];
#pragma unroll
        for (int j = 0; j < PD; ++j)
            v[j] = *(const half8*)(src + (size_t)m[j].x * C + li * 8);
        int eb = e + PD * EG;
        int2 mn[PD];
#pragma unroll
        for (int j = 0; j < PD; ++j) mn[j] = ldmeta(eb + j * EG);
#pragma unroll
        for (int j = 0; j < PD; ++j) {
            float wv = __int_as_float(m[j].y);
#pragma unroll
            for (int q = 0; q < 8; ++q)
                acc[q] = fmaf(wv, (float)v[j][q], acc[q]);
        }
        e = eb;
#pragma unroll
        for (int j = 0; j < PD; ++j) m[j] = mn[j];
    }

    // butterfly-reduce across edge groups
#pragma unroll
    for (int msk = LPE; msk < 64; msk <<= 1)
#pragma unroll
        for (int j = 0; j < 8; ++j)
            acc[j] += __shfl_xor(acc[j], msk);

    if (eg == 0) {
        size_t o = (size_t)r * C + li * 8;
        float res[8];
        half8 av = __builtin_nontemporal_load((const half8*)(A + o));
#pragma unroll
        for (int j = 0; j < 8; ++j) res[j] = scale * acc[j] + (float)av[j];
        if (B) {
            half8 bv = __builtin_nontemporal_load((const half8*)(B + o));
#pragma unroll
            for (int j = 0; j < 8; ++j) res[j] += betaB * (float)bv[j];
        }
        if (bias) {
            float4 b0 = *(const float4*)(bias + li * 8);
            float4 b1 = *(const float4*)(bias + li * 8 + 4);
            res[0] += b0.x; res[1] += b0.y; res[2] += b0.z; res[3] += b0.w;
            res[4] += b1.x; res[5] += b1.y; res[6] += b1.z; res[7] += b1.w;
        }
        if (do_relu)
#pragma unroll
            for (int j = 0; j < 8; ++j) res[j] = fmaxf(res[j], 0.f);
        if (do_lsm) {
            float mx = res[0];
#pragma unroll
            for (int j = 1; j < 8; ++j) mx = fmaxf(mx, res[j]);
            for (int s = 1; s < LPE; s <<= 1) mx = fmaxf(mx, __shfl_xor(mx, s));
            float sum = 0.f;
#pragma unroll
            for (int j = 0; j < 8; ++j) sum += expf(res[j] - mx);
            for (int s = 1; s < LPE; s <<= 1) sum += __shfl_xor(sum, s);
            float lg = mx + logf(sum);
#pragma unroll
            for (int j = 0; j < 8; ++j) res[j] -= lg;
        }
        if (dsth) {   // cached store: this buffer is the next prop's gather source
            half8 hv;
#pragma unroll
            for (int j = 0; j < 8; ++j) hv[j] = (_Float16)res[j];
            *(half8*)(dsth + o) = hv;
        }
        if (dstf) {   // final output: streamed, bypass cache
            floatx4 f0 = {res[0], res[1], res[2], res[3]};
            floatx4 f1 = {res[4], res[5], res[6], res[7]};
            __builtin_nontemporal_store(f0, (floatx4*)(dstf + o));
            __builtin_nontemporal_store(f1, (floatx4*)(dstf + o + 4));
        }
    }
}

// ---------------------------------------------------------------- host launch
extern "C" void kernel_launch(void* const* d_in, const int* in_sizes, int n_in,
                              void* d_out, int out_size, void* d_ws, size_t ws_size,
                              hipStream_t stream) {
    const float* x  = (const float*)d_in[0];   // [NN,128]
    const float* W1 = (const float*)d_in[1];   // [4,128,128]
    const float* b1 = (const float*)d_in[2];   // [128]
    const float* W2 = (const float*)d_in[3];   // [4,128,64]
    const float* b2 = (const float*)d_in[4];   // [64]
    const int* ei   = (const int*)d_in[5];     // [2,NE] int
    const int* erow = ei;
    const int* ecol = ei + NE;
    float* out = (float*)d_out;                // [NN,64]

    char* w = (char*)d_ws;
    size_t off = 0;
    auto alloc = [&](size_t bytes) {
        size_t o = off;
        off += (bytes + 255) & ~(size_t)255;
        return o;
    };
    float* dis     = (float*)(w + alloc((size_t)NN * 4));
    int*   row_ptr = (int*)(w + alloc((size_t)(NN + 1) * 4));
    int*   bcnt    = (int*)(w + alloc((size_t)NB * 4));
    int*   bbase   = (int*)(w + alloc((size_t)(NB + 1) * 4));
    int*   bcur    = (int*)(w + alloc((size_t)NB * 4));
    __half* Wt1    = (__half*)(w + alloc((size_t)512 * 128 * 2));
    __half* Wt2    = (__half*)(w + alloc((size_t)256 * 128 * 2));
    unsigned int* S = (unsigned int*)(w + alloc((size_t)NE * 4));
    int2*  ed      = (int2*)(w + alloc((size_t)NE * 8));
    __half* Y      = (__half*)(w + alloc((size_t)4 * NN * 128 * 2));  // Y0..Y3 fp16
    __half* Y0 = Y;
    __half* Y1 = Y + (size_t)1 * NN * 128;
    __half* Y2 = Y + (size_t)2 * NN * 128;
    __half* Y3 = Y + (size_t)3 * NN * 128;
    __half* Z0 = Y1;
    __half* Z1 = Y1 + (size_t)1 * NN * 64;
    __half* Z2 = Y1 + (size_t)2 * NN * 64;
    __half* Z3 = Y1 + (size_t)3 * NN * 64;

    const int pb  = (NN + 3) / 4;
    const int ebB = (NE + 8191) / 8192;     // 391 blocks for edge passes
    const dim3 g1((NN + 127) / 128, 4);
    const dim3 g2((NN + 127) / 128, 2);

    // ---- graph build: bucketed counting sort, no global per-row atomics
    hipMemsetAsync(bcnt, 0, (size_t)NB * 4, stream);
    k_wt<<<384, 256, 0, stream>>>(W1, W2, Wt1, Wt2);
    k_bcount<<<ebB, 256, 0, stream>>>(erow, bcnt);
    k_bscan<<<1, 256, 0, stream>>>(bcnt, bbase, bcur);
    k_bin<<<ebB, 256, 0, stream>>>(erow, ecol, bcur, S);
    k_rowptr<<<NB, 256, 0, stream>>>(bbase, S, row_ptr, dis);
    k_place<<<NB, 256, 0, stream>>>(row_ptr, dis, S, ed);

    // ---- layer 1
    k_mm<128, float><<<g1, 256, 0, stream>>>(x, Wt1, Y);
    k_prop<128><<<pb, 256, 0, stream>>>(row_ptr, ed, Y3, Y2, nullptr,
                                        nullptr, 2.f, 0.f, 0, 0, Y2, nullptr);
    k_prop<128><<<pb, 256, 0, stream>>>(row_ptr, ed, Y2, Y1, Y3,
                                        nullptr, 2.f, -1.f, 0, 0, Y1, nullptr);
    k_prop<128><<<pb, 256, 0, stream>>>(row_ptr, ed, Y1, Y0, Y2,
                                        b1, 1.f, -1.f, 1, 0, Y0, nullptr);

    // ---- layer 2
    k_mm<64, __half><<<g2, 256, 0, stream>>>(Y0, Wt2, Z0);
    k_prop<64><<<pb, 256, 0, stream>>>(row_ptr, ed, Z3, Z2, nullptr,
                                       nullptr, 2.f, 0.f, 0, 0, Z2, nullptr);
    k_prop<64><<<pb, 256, 0, stream>>>(row_ptr, ed, Z2, Z1, Z3,
                                       nullptr, 2.f, -1.f, 0, 0, Z1, nullptr);
    k_prop<64><<<pb, 256, 0, stream>>>(row_ptr, ed, Z1, Z0, Z2,
                                       b2, 1.f, -1.f, 0, 1, nullptr, out);
}

// Round 8
// 753.862 us; speedup vs baseline: 1.2696x; 1.2696x over previous
//
#include <hip/hip_runtime.h>
#include <hip/hip_bf16.h>
#include <hip/hip_fp16.h>

// ChebNet: N=100000 nodes, E=3.2M edges, K=4, 128 -> 128(relu) -> 64 -> log_softmax
// Clenshaw form: sum_k T_k(L) x @ W_k == Clenshaw(L, y_k), y_k = x @ W_k.
// R8: R7 reverted (PD=4/NT regressed; Little's-law shows the gather path is
//     byte-rate-saturated at ~3.7 TB/s, not latency-bound). Gather SOURCES now
//     stored fp8-e4m3 (half the bytes/row, half the working set); A/B operands,
//     h, and all epilogue math stay fp16/fp32. Producers dual-store fp16+fp8.

#define NN 100000
#define NE 3200000
#define NB 782          // ceil(NN/128) buckets of 128 rows

using half8 = __attribute__((ext_vector_type(8))) _Float16;
using floatx4 = __attribute__((ext_vector_type(4))) float;
using floatx2 = __attribute__((ext_vector_type(2))) float;

// ---------------------------------------------------------------- pass 1: bucket counts
__global__ __launch_bounds__(256) void k_bcount(const int* __restrict__ erow,
                                                int* __restrict__ bcnt) {
    __shared__ int hist[NB];
    const int t = threadIdx.x;
    const int e0 = blockIdx.x * 8192 + t * 32;
    for (int b = t; b < NB; b += 256) hist[b] = 0;
    __syncthreads();
#pragma unroll
    for (int j = 0; j < 8; ++j) {
        int idx = e0 + j * 4;
        if (idx < NE) {
            int4 r4 = *(const int4*)(erow + idx);
            atomicAdd(&hist[r4.x >> 7], 1);
            atomicAdd(&hist[r4.y >> 7], 1);
            atomicAdd(&hist[r4.z >> 7], 1);
            atomicAdd(&hist[r4.w >> 7], 1);
        }
    }
    __syncthreads();
    for (int b = t; b < NB; b += 256)
        if (hist[b] > 0) atomicAdd(&bcnt[b], hist[b]);
}

// ---------------------------------------------------------------- scan bucket counts -> bbase, bcur
__global__ __launch_bounds__(256) void k_bscan(const int* __restrict__ bcnt,
                                               int* __restrict__ bbase,
                                               int* __restrict__ bcur) {
    __shared__ int sm[256];
    const int t = threadIdx.x;
    int v[4];
    int s = 0;
#pragma unroll
    for (int j = 0; j < 4; ++j) {
        int idx = t * 4 + j;
        v[j] = (idx < NB) ? bcnt[idx] : 0;
        s += v[j];
    }
    sm[t] = s; __syncthreads();
    for (int st = 1; st < 256; st <<= 1) {
        int a = (t >= st) ? sm[t - st] : 0;
        __syncthreads();
        sm[t] += a;
        __syncthreads();
    }
    int ex = (t == 0) ? 0 : sm[t - 1];
#pragma unroll
    for (int j = 0; j < 4; ++j) {
        int idx = t * 4 + j;
        if (idx < NB) { bbase[idx] = ex; bcur[idx] = ex; }
        ex += v[j];
    }
    if (t == 255) bbase[NB] = NE;
}

// ---------------------------------------------------------------- pass 2: bucket edges into staging S
__global__ __launch_bounds__(256) void k_bin(const int* __restrict__ erow,
                                             const int* __restrict__ ecol,
                                             int* __restrict__ bcur,
                                             unsigned int* __restrict__ S) {
    __shared__ int hist[NB];
    __shared__ int base[NB];
    __shared__ int cnt[NB];
    const int t = threadIdx.x;
    const int e0 = blockIdx.x * 8192 + t * 32;

    for (int b = t; b < NB; b += 256) { hist[b] = 0; cnt[b] = 0; }
    __syncthreads();

#pragma unroll
    for (int j = 0; j < 8; ++j) {
        int idx = e0 + j * 4;
        if (idx < NE) {
            int4 r4 = *(const int4*)(erow + idx);
            atomicAdd(&hist[r4.x >> 7], 1);
            atomicAdd(&hist[r4.y >> 7], 1);
            atomicAdd(&hist[r4.z >> 7], 1);
            atomicAdd(&hist[r4.w >> 7], 1);
        }
    }
    __syncthreads();

    for (int b = t; b < NB; b += 256)
        if (hist[b] > 0) base[b] = atomicAdd(&bcur[b], hist[b]);
    __syncthreads();

#pragma unroll
    for (int j = 0; j < 8; ++j) {
        int idx = e0 + j * 4;
        if (idx < NE) {
            int4 r4 = *(const int4*)(erow + idx);
            int4 c4 = *(const int4*)(ecol + idx);
            int rr[4] = {r4.x, r4.y, r4.z, r4.w};
            int cc[4] = {c4.x, c4.y, c4.z, c4.w};
#pragma unroll
            for (int q = 0; q < 4; ++q) {
                int b = rr[q] >> 7;
                int off = atomicAdd(&cnt[b], 1);
                S[base[b] + off] = ((unsigned)(rr[q] & 127) << 17) | (unsigned)cc[q];
            }
        }
    }
}

// ---------------------------------------------------------------- per-bucket row_ptr + dis
__global__ __launch_bounds__(256) void k_rowptr(const int* __restrict__ bbase,
                                                const unsigned int* __restrict__ S,
                                                int* __restrict__ row_ptr,
                                                float* __restrict__ dis) {
    __shared__ int hist[128];
    __shared__ int sc[128];
    const int b = blockIdx.x;
    const int t = threadIdx.x;
    const int r0 = b * 128;
    const int rows = (r0 + 128 <= NN) ? 128 : (NN - r0);
    if (t < 128) hist[t] = 0;
    __syncthreads();
    const int s = bbase[b];
    const int e = bbase[b + 1];
    for (int i = s + t; i < e; i += 256)
        atomicAdd(&hist[S[i] >> 17], 1);
    __syncthreads();
    if (t < 128) sc[t] = hist[t];
    __syncthreads();
    for (int st = 1; st < 128; st <<= 1) {
        int a = (t >= st && t < 128) ? sc[t - st] : 0;
        __syncthreads();
        if (t < 128) sc[t] += a;
        __syncthreads();
    }
    if (t < rows) {
        row_ptr[r0 + t] = s + ((t == 0) ? 0 : sc[t - 1]);
        int d = hist[t];
        dis[r0 + t] = (d > 0) ? rsqrtf((float)d) : 0.0f;
    }
    if (b == 0 && t == 0) row_ptr[NN] = NE;
}

// ---------------------------------------------------------------- pass 3: within-bucket placement
__global__ __launch_bounds__(256) void k_place(const int* __restrict__ row_ptr,
                                               const float* __restrict__ dis,
                                               const unsigned int* __restrict__ S,
                                               int2* __restrict__ ed) {
    __shared__ int cur[128];
    __shared__ float disr[128];
    const int b = blockIdx.x;
    const int t = threadIdx.x;
    const int r0 = b * 128;
    const int rows = (r0 + 128 <= NN) ? 128 : (NN - r0);
    if (t < rows) {
        cur[t] = row_ptr[r0 + t];
        disr[t] = dis[r0 + t];
    }
    __syncthreads();
    const int s = row_ptr[r0];
    const int e = row_ptr[r0 + rows];
    for (int i = s + t; i < e; i += 256) {
        unsigned v = S[i];
        int c = v & 131071;
        int rl = v >> 17;
        float wv = -disr[rl] * dis[c];
        int pos = atomicAdd(&cur[rl], 1);
        ed[pos] = make_int2(c, __float_as_int(wv));
    }
}

// ---------------------------------------------------------------- W transpose -> fp16 [N][K]
__global__ void k_wt(const float* __restrict__ W1, const float* __restrict__ W2,
                     __half* __restrict__ Wt1, __half* __restrict__ Wt2) {
    int tid = blockIdx.x * 256 + threadIdx.x;
    if (tid < 512 * 128) {
        int n = tid >> 7, k = tid & 127;
        Wt1[tid] = __float2half_rn(W1[(((n >> 7) * 128) + k) * 128 + (n & 127)]);
    } else {
        int t2 = tid - 512 * 128;
        if (t2 < 256 * 128) {
            int n = t2 >> 7, k = t2 & 127;
            Wt2[t2] = __float2half_rn(W2[(((n >> 6) * 128) + k) * 64 + (n & 63)]);
        }
    }
}

// ---------------------------------------------------------------- MFMA GEMM  Y = X @ Wt^T
// Writes fp16 Y (per-k planes) + fp8 gather copies for k=1..3 (Y8 planes, k-1 indexed).
template <int OUTC, typename TX>
__global__ __launch_bounds__(256) void k_mm(const TX* __restrict__ X,
                                            const __half* __restrict__ Wt,
                                            __half* __restrict__ Y,
                                            unsigned char* __restrict__ Y8) {
    __shared__ __half As[128 * 136];
    const int t = threadIdx.x;
    const int lane = t & 63;
    const int w = t >> 6;
    const int r0 = blockIdx.x * 128;
    const int n0 = blockIdx.y * 128;

    if constexpr (sizeof(TX) == 4) {
#pragma unroll
        for (int i = 0; i < 16; ++i) {
            int v = t + i * 256;
            int row = v >> 5, c4 = v & 31;
            float4 xv = make_float4(0.f, 0.f, 0.f, 0.f);
            if (r0 + row < NN) xv = *(const float4*)((const float*)X + (size_t)(r0 + row) * 128 + c4 * 4);
            __half2* p = (__half2*)(As + row * 136 + c4 * 4);
            p[0] = __float22half2_rn(make_float2(xv.x, xv.y));
            p[1] = __float22half2_rn(make_float2(xv.z, xv.w));
        }
    } else {
#pragma unroll
        for (int i = 0; i < 8; ++i) {
            int v = t + i * 256;
            int row = v >> 4, c8 = v & 15;
            uint4 xv = make_uint4(0, 0, 0, 0);
            if (r0 + row < NN) xv = *(const uint4*)((const __half*)X + (size_t)(r0 + row) * 128 + c8 * 8);
            *(uint4*)(As + row * 136 + c8 * 8) = xv;
        }
    }
    __syncthreads();

    const int m = lane & 15, quad = lane >> 4;
    floatx4 acc[2][8] = {};
    const __half* wb = Wt + (size_t)(n0 + m) * 128 + quad * 8;
    const __half* ab = As + (w * 32 + m) * 136 + quad * 8;

#pragma unroll
    for (int ks = 0; ks < 4; ++ks) {
        half8 a0 = *(const half8*)(ab + ks * 32);
        half8 a1 = *(const half8*)(ab + 16 * 136 + ks * 32);
#pragma unroll
        for (int nt = 0; nt < 8; ++nt) {
            half8 b = *(const half8*)(wb + (size_t)nt * 16 * 128 + ks * 32);
            acc[0][nt] = __builtin_amdgcn_mfma_f32_16x16x32_f16(a0, b, acc[0][nt], 0, 0, 0);
            acc[1][nt] = __builtin_amdgcn_mfma_f32_16x16x32_f16(a1, b, acc[1][nt], 0, 0, 0);
        }
    }

    __syncthreads();
#pragma unroll
    for (int mt = 0; mt < 2; ++mt)
#pragma unroll
        for (int nt = 0; nt < 8; ++nt)
#pragma unroll
            for (int rg = 0; rg < 4; ++rg)
                As[(w * 32 + mt * 16 + quad * 4 + rg) * 136 + nt * 16 + m] =
                    __float2half_rn(acc[mt][nt][rg]);
    __syncthreads();

#pragma unroll
    for (int i = 0; i < 8; ++i) {
        int v = t + i * 256;
        int row = v >> 4, c8 = v & 15;
        int node = r0 + row;
        if (node < NN) {
            uint4 val = *(const uint4*)(As + row * 136 + c8 * 8);
            int ng = n0 + c8 * 8;
            int kidx = (OUTC == 128) ? (ng >> 7) : (ng >> 6);
            int cin = ng & (OUTC - 1);
            __half* dst = Y + ((size_t)kidx * NN + node) * OUTC + cin;
            *(uint4*)dst = val;
            if (kidx > 0) {   // fp8 gather copy (planes k=1..3)
                float2 f01 = __half22float2(*(__half2*)&val.x);
                float2 f23 = __half22float2(*(__half2*)&val.y);
                float2 f45 = __half22float2(*(__half2*)&val.z);
                float2 f67 = __half22float2(*(__half2*)&val.w);
                unsigned lo = 0, hi = 0;
                lo = __builtin_amdgcn_cvt_pk_fp8_f32(f01.x, f01.y, lo, false);
                lo = __builtin_amdgcn_cvt_pk_fp8_f32(f23.x, f23.y, lo, true);
                hi = __builtin_amdgcn_cvt_pk_fp8_f32(f45.x, f45.y, hi, false);
                hi = __builtin_amdgcn_cvt_pk_fp8_f32(f67.x, f67.y, hi, true);
                unsigned char* d8 = Y8 + ((size_t)(kidx - 1) * NN + node) * OUTC + cin;
                *(uint2*)d8 = make_uint2(lo, hi);
            }
        }
    }
}

// ---------------------------------------------------------------- propagation (SpMM, fp8 gather src)
// dst[r][:] = scale * sum_e w_e * src8[col_e][:] + A[r][:] + betaB*B[r][:] (+bias, relu, lsm)
template <int C>
__global__ __launch_bounds__(256) void k_prop(const int* __restrict__ rp,
                                              const int2* __restrict__ ed,
                                              const unsigned char* __restrict__ src8,
                                              const __half* __restrict__ A,
                                              const __half* __restrict__ B,
                                              const float* __restrict__ bias,
                                              float scale, float betaB, int do_relu,
                                              int do_lsm,
                                              __half* __restrict__ dsth,
                                              unsigned char* __restrict__ dst8,
                                              float* __restrict__ dstf) {
    constexpr int LPE = C / 8;     // lanes per edge (8 fp8 ch each)
    constexpr int EG = 64 / LPE;   // concurrent edges per wave
    const int wid = threadIdx.x >> 6;
    const int lane = threadIdx.x & 63;
    const int r = blockIdx.x * 4 + wid;
    if (r >= NN) return;
    const int e0 = rp[r], e1 = rp[r + 1];
    const int eg = lane / LPE, li = lane % LPE;

    float acc[8] = {};
    int e = e0 + eg;
    int2 el0 = (e < e1) ? ed[e] : make_int2(0, 0);
    int2 el1 = (e + EG < e1) ? ed[e + EG] : make_int2(0, 0);
    const int nit2 = (e1 - e0 + 2 * EG - 1) / (2 * EG);   // wave-uniform
    for (int it = 0; it < nit2; ++it) {
        uint2 u0 = *(const uint2*)(src8 + (size_t)el0.x * C + li * 8);
        uint2 u1 = *(const uint2*)(src8 + (size_t)el1.x * C + li * 8);
        int en0 = e + 2 * EG, en1 = e + 3 * EG;
        int2 p0 = (en0 < e1) ? ed[en0] : make_int2(0, 0);
        int2 p1 = (en1 < e1) ? ed[en1] : make_int2(0, 0);
        float w0 = __int_as_float(el0.y);
        float w1 = __int_as_float(el1.y);
        {
            floatx2 q0 = __builtin_amdgcn_cvt_pk_f32_fp8(u0.x, false);
            floatx2 q1 = __builtin_amdgcn_cvt_pk_f32_fp8(u0.x, true);
            floatx2 q2 = __builtin_amdgcn_cvt_pk_f32_fp8(u0.y, false);
            floatx2 q3 = __builtin_amdgcn_cvt_pk_f32_fp8(u0.y, true);
            acc[0] = fmaf(w0, q0[0], acc[0]); acc[1] = fmaf(w0, q0[1], acc[1]);
            acc[2] = fmaf(w0, q1[0], acc[2]); acc[3] = fmaf(w0, q1[1], acc[3]);
            acc[4] = fmaf(w0, q2[0], acc[4]); acc[5] = fmaf(w0, q2[1], acc[5]);
            acc[6] = fmaf(w0, q3[0], acc[6]); acc[7] = fmaf(w0, q3[1], acc[7]);
        }
        {
            floatx2 q0 = __builtin_amdgcn_cvt_pk_f32_fp8(u1.x, false);
            floatx2 q1 = __builtin_amdgcn_cvt_pk_f32_fp8(u1.x, true);
            floatx2 q2 = __builtin_amdgcn_cvt_pk_f32_fp8(u1.y, false);
            floatx2 q3 = __builtin_amdgcn_cvt_pk_f32_fp8(u1.y, true);
            acc[0] = fmaf(w1, q0[0], acc[0]); acc[1] = fmaf(w1, q0[1], acc[1]);
            acc[2] = fmaf(w1, q1[0], acc[2]); acc[3] = fmaf(w1, q1[1], acc[3]);
            acc[4] = fmaf(w1, q2[0], acc[4]); acc[5] = fmaf(w1, q2[1], acc[5]);
            acc[6] = fmaf(w1, q3[0], acc[6]); acc[7] = fmaf(w1, q3[1], acc[7]);
        }
        e = en0; el0 = p0; el1 = p1;
    }

    // butterfly-reduce across edge groups
#pragma unroll
    for (int msk = LPE; msk < 64; msk <<= 1)
#pragma unroll
        for (int j = 0; j < 8; ++j)
            acc[j] += __shfl_xor(acc[j], msk);

    if (eg == 0) {
        size_t o = (size_t)r * C + li * 8;
        float res[8];
        half8 av = *(const half8*)(A + o);
#pragma unroll
        for (int j = 0; j < 8; ++j) res[j] = scale * acc[j] + (float)av[j];
        if (B) {
            half8 bv = *(const half8*)(B + o);
#pragma unroll
            for (int j = 0; j < 8; ++j) res[j] += betaB * (float)bv[j];
        }
        if (bias) {
            float4 b0 = *(const float4*)(bias + li * 8);
            float4 b1 = *(const float4*)(bias + li * 8 + 4);
            res[0] += b0.x; res[1] += b0.y; res[2] += b0.z; res[3] += b0.w;
            res[4] += b1.x; res[5] += b1.y; res[6] += b1.z; res[7] += b1.w;
        }
        if (do_relu)
#pragma unroll
            for (int j = 0; j < 8; ++j) res[j] = fmaxf(res[j], 0.f);
        if (do_lsm) {
            float mx = res[0];
#pragma unroll
            for (int j = 1; j < 8; ++j) mx = fmaxf(mx, res[j]);
            for (int s = 1; s < LPE; s <<= 1) mx = fmaxf(mx, __shfl_xor(mx, s));
            float sum = 0.f;
#pragma unroll
            for (int j = 0; j < 8; ++j) sum += expf(res[j] - mx);
            for (int s = 1; s < LPE; s <<= 1) sum += __shfl_xor(sum, s);
            float lg = mx + logf(sum);
#pragma unroll
            for (int j = 0; j < 8; ++j) res[j] -= lg;
        }
        if (dsth) {
            half8 hv;
#pragma unroll
            for (int j = 0; j < 8; ++j) hv[j] = (_Float16)res[j];
            *(half8*)(dsth + o) = hv;
        }
        if (dst8) {   // fp8 copy for the next prop's gather
            unsigned lo = 0, hi = 0;
            lo = __builtin_amdgcn_cvt_pk_fp8_f32(res[0], res[1], lo, false);
            lo = __builtin_amdgcn_cvt_pk_fp8_f32(res[2], res[3], lo, true);
            hi = __builtin_amdgcn_cvt_pk_fp8_f32(res[4], res[5], hi, false);
            hi = __builtin_amdgcn_cvt_pk_fp8_f32(res[6], res[7], hi, true);
            *(uint2*)(dst8 + o) = make_uint2(lo, hi);
        }
        if (dstf) {
            *(float4*)(dstf + o) = make_float4(res[0], res[1], res[2], res[3]);
            *(float4*)(dstf + o + 4) = make_float4(res[4], res[5], res[6], res[7]);
        }
    }
}

// ---------------------------------------------------------------- host launch
extern "C" void kernel_launch(void* const* d_in, const int* in_sizes, int n_in,
                              void* d_out, int out_size, void* d_ws, size_t ws_size,
                              hipStream_t stream) {
    const float* x  = (const float*)d_in[0];   // [NN,128]
    const float* W1 = (const float*)d_in[1];   // [4,128,128]
    const float* b1 = (const float*)d_in[2];   // [128]
    const float* W2 = (const float*)d_in[3];   // [4,128,64]
    const float* b2 = (const float*)d_in[4];   // [64]
    const int* ei   = (const int*)d_in[5];     // [2,NE] int
    const int* erow = ei;
    const int* ecol = ei + NE;
    float* out = (float*)d_out;                // [NN,64]

    char* w = (char*)d_ws;
    size_t off = 0;
    auto alloc = [&](size_t bytes) {
        size_t o = off;
        off += (bytes + 255) & ~(size_t)255;
        return o;
    };
    float* dis     = (float*)(w + alloc((size_t)NN * 4));
    int*   row_ptr = (int*)(w + alloc((size_t)(NN + 1) * 4));
    int*   bcnt    = (int*)(w + alloc((size_t)NB * 4));
    int*   bbase   = (int*)(w + alloc((size_t)(NB + 1) * 4));
    int*   bcur    = (int*)(w + alloc((size_t)NB * 4));
    __half* Wt1    = (__half*)(w + alloc((size_t)512 * 128 * 2));
    __half* Wt2    = (__half*)(w + alloc((size_t)256 * 128 * 2));
    unsigned int* S = (unsigned int*)(w + alloc((size_t)NE * 4));
    int2*  ed      = (int2*)(w + alloc((size_t)NE * 8));
    __half* Y      = (__half*)(w + alloc((size_t)4 * NN * 128 * 2));  // fp16 planes
    unsigned char* Y8 = (unsigned char*)(w + alloc((size_t)3 * NN * 128)); // fp8 k=1..3
    unsigned char* Z8 = (unsigned char*)(w + alloc((size_t)3 * NN * 64));  // fp8 k=1..3
    __half* Y0 = Y;
    __half* Y1 = Y + (size_t)1 * NN * 128;
    __half* Y2 = Y + (size_t)2 * NN * 128;
    __half* Y3 = Y + (size_t)3 * NN * 128;
    __half* Z0 = Y1;                          // layer-2 fp16 planes reuse Y1..Y2
    __half* Z1 = Y1 + (size_t)1 * NN * 64;
    __half* Z2 = Y1 + (size_t)2 * NN * 64;
    __half* Z3 = Y1 + (size_t)3 * NN * 64;
    auto Y8p = [&](int k) { return Y8 + (size_t)(k - 1) * NN * 128; };
    auto Z8p = [&](int k) { return Z8 + (size_t)(k - 1) * NN * 64; };

    const int pb  = (NN + 3) / 4;
    const int ebB = (NE + 8191) / 8192;
    const dim3 g1((NN + 127) / 128, 4);
    const dim3 g2((NN + 127) / 128, 2);

    // ---- graph build: bucketed counting sort, no global per-row atomics
    hipMemsetAsync(bcnt, 0, (size_t)NB * 4, stream);
    k_wt<<<384, 256, 0, stream>>>(W1, W2, Wt1, Wt2);
    k_bcount<<<ebB, 256, 0, stream>>>(erow, bcnt);
    k_bscan<<<1, 256, 0, stream>>>(bcnt, bbase, bcur);
    k_bin<<<ebB, 256, 0, stream>>>(erow, ecol, bcur, S);
    k_rowptr<<<NB, 256, 0, stream>>>(bbase, S, row_ptr, dis);
    k_place<<<NB, 256, 0, stream>>>(row_ptr, dis, S, ed);

    // ---- layer 1: y_k = x @ W1[k]; Clenshaw in 128-ch, fp8 gather sources
    k_mm<128, float><<<g1, 256, 0, stream>>>(x, Wt1, Y, Y8);
    // b2 = y2 + 2 P y3            (fp16 -> Y2, fp8 -> plane 2)
    k_prop<128><<<pb, 256, 0, stream>>>(row_ptr, ed, Y8p(3), Y2, nullptr,
                                        nullptr, 2.f, 0.f, 0, 0, Y2, Y8p(2), nullptr);
    // b1 = y1 + 2 P b2 - y3       (fp16 -> Y1, fp8 -> plane 1)
    k_prop<128><<<pb, 256, 0, stream>>>(row_ptr, ed, Y8p(2), Y1, Y3,
                                        nullptr, 2.f, -1.f, 0, 0, Y1, Y8p(1), nullptr);
    // h = relu(y0 + P b1 - b2 + bias1)  (fp16 only; h feeds GEMM-2)
    k_prop<128><<<pb, 256, 0, stream>>>(row_ptr, ed, Y8p(1), Y0, Y2,
                                        b1, 1.f, -1.f, 1, 0, Y0, nullptr, nullptr);

    // ---- layer 2: z_k = h @ W2[k]; Clenshaw in 64-ch, fp8 gather sources
    k_mm<64, __half><<<g2, 256, 0, stream>>>(Y0, Wt2, Z0, Z8);
    k_prop<64><<<pb, 256, 0, stream>>>(row_ptr, ed, Z8p(3), Z2, nullptr,
                                       nullptr, 2.f, 0.f, 0, 0, Z2, Z8p(2), nullptr);
    k_prop<64><<<pb, 256, 0, stream>>>(row_ptr, ed, Z8p(2), Z1, Z3,
                                       nullptr, 2.f, -1.f, 0, 0, Z1, Z8p(1), nullptr);
    k_prop<64><<<pb, 256, 0, stream>>>(row_ptr, ed, Z8p(1), Z0, Z2,
                                       b2, 1.f, -1.f, 0, 1, nullptr, nullptr, out);
}